// Round 15
// baseline (105.050 us; speedup 1.0000x reference)
//
#include <hip/hip_runtime.h>

typedef unsigned short u16;
typedef __attribute__((ext_vector_type(4))) float f32x4;
typedef __attribute__((ext_vector_type(8))) short s16x8;

__device__ inline float bf2f(u16 u) {
    unsigned v = ((unsigned)u) << 16;
    return __builtin_bit_cast(float, v);
}
__device__ inline u16 f2bf(float f) {
    unsigned u = __builtin_bit_cast(unsigned, f);
    unsigned r = (u + 0x7FFFu + ((u >> 16) & 1u)) >> 16;
    return (u16)r;
}

typedef const __attribute__((address_space(1))) void* gptr_t;
typedef __attribute__((address_space(3))) void* lptr_t;
__device__ inline void gload16(const u16* gp, u16* lp) {
    __builtin_amdgcn_global_load_lds((gptr_t)gp, (lptr_t)lp, 16, 0, 0);
}

// ---------------- wsb_prep: Wsb = bf16(stem_w) — the only stem-GEMM dependency ----------
__global__ __launch_bounds__(256) void wsb_prep(const float* __restrict__ stem_w,
                                                u16* __restrict__ Wsb) {
    int base = blockIdx.x * 1024;
#pragma unroll
    for (int it = 0; it < 4; ++it) {
        int i = base + it * 256 + threadIdx.x;
        Wsb[i] = f2bf(stem_w[i]);
    }
}

// ============ stem_prep (r14 verified): stem GEMM + independent prep, one launch =========
__global__ __launch_bounds__(256, 4) void stem_prep(
    const float* __restrict__ x, const int* __restrict__ idx,
    const u16* __restrict__ Wsb, const float* __restrict__ stem_b,
    const float* __restrict__ cls_conv_w, const float* __restrict__ cls_conv_b,
    const float* __restrict__ reg_conv_w, const float* __restrict__ reg_conv_b,
    const float* __restrict__ cls_pred_w, const float* __restrict__ cls_pred_b,
    const float* __restrict__ reg_pred_w, const float* __restrict__ reg_pred_b,
    const float* __restrict__ obj_pred_w, const float* __restrict__ obj_pred_b,
    u16* __restrict__ stem, u16* __restrict__ Wc, u16* __restrict__ Wf,
    int* __restrict__ rowoff, float* __restrict__ bc, float* __restrict__ bp,
    u16* __restrict__ zpage) {
    __shared__ __align__(16) u16 lA[128 * 72];
    __shared__ __align__(16) u16 lB[64 * 64];
    const int blk = blockIdx.x;
    const int t = threadIdx.x;

    if (blk < 1600) {                      // ---- stem GEMM (r10 body verbatim) ----
        const int lane = t & 63;
        const int wid = t >> 6;
        const int wm = wid >> 1, wn = wid & 1;
        const int bx  = blk % 400;
        const int n0  = (blk / 400) * 64;
        const int b   = bx / 50;
        const int hwb = (bx % 50) * 128;

        const int srw = lane >> 3;
        const int cc  = lane & 7;
        const int gch = (cc ^ srw) * 8;
        const int arow = lane & 15;
        const int khi  = lane >> 4;
        const int sa   = arow & 7;

        const float* xb = x + (size_t)b * 256 * 6400 + hwb;
        const u16* Bp = Wsb + (size_t)(n0 + wid * 8 + srw) * 256 + gch;

        f32x4 acc[4][2] = {};

        for (int k0 = 0; k0 < 256; k0 += 64) {
#pragma unroll
            for (int r = 0; r < 2; ++r)
                gload16(Bp + (size_t)(r * 32) * 256 + k0,
                        lB + (r * 32 + wid * 8) * 64);
#pragma unroll
            for (int u = 0; u < 4; ++u) {
                const int hw  = (u & 1) * 64 + lane;
                const int oct = (u >> 1) * 4 + wid;
                union { u16 s[8]; s16x8 v; } pk;
#pragma unroll
                for (int jj = 0; jj < 8; ++jj)
                    pk.s[jj] = f2bf(xb[(size_t)(k0 + oct * 8 + jj) * 6400 + hw]);
                *(s16x8*)&lA[hw * 72 + oct * 8] = pk.v;
            }
            __syncthreads();
            s16x8 af[2][4], bfr[2][2];
#pragma unroll
            for (int f = 0; f < 4; ++f) {
                int ra = (wm * 64 + f * 16 + arow) * 72;
#pragma unroll
                for (int ks = 0; ks < 2; ++ks)
                    af[ks][f] = *(const s16x8*)&lA[ra + (ks * 4 + khi) * 8];
            }
#pragma unroll
            for (int jj = 0; jj < 2; ++jj) {
                int rb2 = (wn * 32 + jj * 16 + arow) * 64;
#pragma unroll
                for (int ks = 0; ks < 2; ++ks) {
                    int q = ks * 4 + khi;
                    bfr[ks][jj] = *(const s16x8*)&lB[rb2 + ((q ^ sa) << 3)];
                }
            }
#pragma unroll
            for (int ks = 0; ks < 2; ++ks)
#pragma unroll
                for (int i = 0; i < 4; ++i)
#pragma unroll
                    for (int jj = 0; jj < 2; ++jj)
                        acc[i][jj] = __builtin_amdgcn_mfma_f32_16x16x32_bf16(
                            af[ks][i], bfr[ks][jj], acc[i][jj], 0, 0, 0);
            __syncthreads();
        }

#pragma unroll
        for (int i = 0; i < 4; ++i) {
            int lr0 = wm * 64 + i * 16 + khi * 4;
#pragma unroll
            for (int jj = 0; jj < 2; ++jj) {
                int gc = n0 + wn * 32 + jj * 16 + arow;
                float bb = stem_b[gc];
#pragma unroll
                for (int r = 0; r < 4; ++r) {
                    float v = acc[i][jj][r] + bb;
                    v = v / (1.0f + __expf(-v));
                    stem[(size_t)(b * 6400 + hwb + lr0 + r) * 256 + gc] = f2bf(v);
                }
            }
        }
    } else if (blk < 2112) {               // ---- Wc permute ----
        int o = blk - 1600;
        const float* src = (o < 256) ? (cls_conv_w + (size_t)o * 2304)
                                     : (reg_conv_w + (size_t)(o - 256) * 2304);
        u16* dst = Wc + (size_t)o * 2304;
#pragma unroll
        for (int it = 0; it < 9; ++it) {
            int kk = it * 256 + t;
            int j = kk >> 8, c = kk & 255;
            dst[kk] = f2bf(src[c * 9 + j]);
        }
    } else if (blk < 2688) {               // ---- rowoff ----
        int i = (blk - 2112) * 256 + t;
        int n = i / 9, j = i % 9;
        int b = idx[n * 3 + 0], y = idx[n * 3 + 1], xx0 = idx[n * 3 + 2];
        int yy = y + j / 3 - 1;
        int xx = xx0 + j % 3 - 1;
        rowoff[i] = ((unsigned)yy < 80u && (unsigned)xx < 80u)
                        ? (b * 6400 + yy * 80 + xx) * 256 : -1;
    } else if (blk < 2720) {               // ---- Wf ----
        int base = (blk - 2688) * 2048;
#pragma unroll
        for (int it = 0; it < 8; ++it) {
            int i = base + it * 256 + t;
            int o = i >> 9, k = i & 511;
            float v = 0.f;
            if (o < 4)       { if (k >= 256) v = reg_pred_w[o * 256 + (k - 256)]; }
            else if (o == 4) { if (k >= 256) v = obj_pred_w[k - 256]; }
            else if (o < 85) { if (k < 256)  v = cls_pred_w[(o - 5) * 256 + k]; }
            Wf[i] = f2bf(v);
        }
    } else {                               // ---- biases + zero page ----
        for (int i = t; i < 512; i += 256)
            bc[i] = (i < 256) ? cls_conv_b[i] : reg_conv_b[i - 256];
        if (t < 128) {
            float v = 0.f;
            if (t < 4) v = reg_pred_b[t];
            else if (t == 4) v = obj_pred_b[0];
            else if (t < 85) v = cls_pred_b[t - 5];
            bp[t] = v;
        }
        zpage[t] = 0;
    }
}

// ---------------- K3: tri-buffer BK=32, counted vmcnt(3), 4 blocks/CU preserved ---------
// feat = silu( gather(stem)[m,:] @ Wc^T + bc ).  BM=128, BN=64, BK=32, grid (128,8).
// LDS 36,864B -> full 1024-block residency (the r13/r8 lesson).  Per step: stage
// step s+2 (3 gloads/wave) -> 8 MFMA on buf[s%3] -> vmcnt(3)+s_barrier (keeps the
// just-issued stage in flight; only stage s+1 is guaranteed landed).  Fully
// unrolled 72 steps so buffer/tap/vmcnt indices are all compile-time (rule 20).
// Swizzle for 64B rows: chunk' = chunk ^ ((row>>1)&3); inverse on global source.
__global__ __launch_bounds__(256, 4) void gemm_conv(
    const u16* __restrict__ stem, const int* __restrict__ rowoff,
    const u16* __restrict__ zpage, const u16* __restrict__ B,
    const float* __restrict__ bias, u16* __restrict__ D) {
    __shared__ __align__(16) u16 lA[3][128 * 32];
    __shared__ __align__(16) u16 lB[3][64 * 32];
    const int tid = threadIdx.x;
    const int lane = tid & 63;
    const int wid = tid >> 6;
    const int wm = wid >> 1, wn = wid & 1;
    const int m0 = blockIdx.x * 128;
    const int n0 = blockIdx.y * 64;

    const int srw = lane >> 2;              // 0..15 staging row within 16-row group
    const int cc  = lane & 3;               // staging chunk slot (16B)
    const int swz = (srw >> 1) & 3;
    const int gch = (cc ^ swz) * 8;         // inverse-swizzled source chunk (elems)
    const int arow = lane & 15;
    const int khi  = lane >> 4;             // 0..3 logical k-chunk
    const int sa   = (arow >> 1) & 3;
    const int rq   = (khi ^ sa) << 3;       // swizzled read elem offset

    int ro[2][9];
#pragma unroll
    for (int r = 0; r < 2; ++r) {
        const int rb = (m0 + r * 64 + wid * 16 + srw) * 9;
#pragma unroll
        for (int j = 0; j < 9; ++j) ro[r][j] = rowoff[rb + j];
    }
    const u16* Bp = B + (size_t)(n0 + wid * 16 + srw) * 2304 + gch;

    f32x4 acc[4][2] = {};

#define STAGE(TS, BI)                                                           \
    {   const int c0_ = ((TS) & 7) << 5;                                        \
        const int jt_ = (TS) >> 3;                                              \
        _Pragma("unroll")                                                       \
        for (int r = 0; r < 2; ++r) {                                           \
            int roff_ = ro[r][jt_];                                             \
            const u16* s_ = (roff_ < 0) ? (zpage + gch)                         \
                                        : (stem + roff_ + c0_ + gch);           \
            gload16(s_, &lA[BI][(r * 64 + wid * 16) * 32]);                     \
        }                                                                       \
        gload16(Bp + (TS) * 32, &lB[BI][(wid * 16) * 32]); }

    // prologue: stage tiles 0,1; wait stage(0) only (stage(1)'s 3 stay in flight)
    STAGE(0, 0);
    STAGE(1, 1);
    asm volatile("s_waitcnt vmcnt(3)" ::: "memory");
    __builtin_amdgcn_s_barrier();

#pragma unroll
    for (int s = 0; s < 72; ++s) {
        if (s + 2 < 72) STAGE(s + 2, (s + 2) % 3);
        const int bi = s % 3;
        s16x8 af[4], bf[2];
#pragma unroll
        for (int f = 0; f < 4; ++f)
            af[f] = *(const s16x8*)&lA[bi][(wm * 64 + f * 16 + arow) * 32 + rq];
#pragma unroll
        for (int jj = 0; jj < 2; ++jj)
            bf[jj] = *(const s16x8*)&lB[bi][(wn * 32 + jj * 16 + arow) * 32 + rq];
#pragma unroll
        for (int i = 0; i < 4; ++i)
#pragma unroll
            for (int jj = 0; jj < 2; ++jj)
                acc[i][jj] = __builtin_amdgcn_mfma_f32_16x16x32_bf16(
                    af[i], bf[jj], acc[i][jj], 0, 0, 0);
        if (s < 70) {
            asm volatile("s_waitcnt vmcnt(3)" ::: "memory");
            __builtin_amdgcn_s_barrier();
        } else if (s == 70) {
            asm volatile("s_waitcnt vmcnt(0)" ::: "memory");
            __builtin_amdgcn_s_barrier();
        }
    }
#undef STAGE

#pragma unroll
    for (int i = 0; i < 4; ++i) {
        int gr0 = m0 + wm * 64 + i * 16 + khi * 4;
#pragma unroll
        for (int jj = 0; jj < 2; ++jj) {
            int gc = n0 + wn * 32 + jj * 16 + arow;
            float bb = bias[gc];
#pragma unroll
            for (int r = 0; r < 4; ++r) {
                float v = acc[i][jj][r] + bb;
                v = v / (1.0f + __expf(-v));
                D[(size_t)(gr0 + r) * 512 + gc] = f2bf(v);
            }
        }
    }
}

// ---------------- K4 (r10 verified): out[m, p<85] = feat[m,:] @ Wf^T + bp ----------------
__global__ __launch_bounds__(256, 4) void gemm_pred(
    const u16* __restrict__ A, const u16* __restrict__ B,
    const float* __restrict__ bias, float* __restrict__ D) {
    __shared__ __align__(16) u16 lA[64 * 64];
    __shared__ __align__(16) u16 lB[64 * 64];
    const int tid = threadIdx.x;
    const int lane = tid & 63;
    const int wid = tid >> 6;
    const int wm = wid >> 1, wn = wid & 1;
    const int m0 = blockIdx.x * 64;
    const int n0 = blockIdx.y * 64;

    const int srw = lane >> 3;
    const int cc  = lane & 7;
    const int arow = lane & 15;
    const int khi  = lane >> 4;

    f32x4 acc[2][2] = {};

    for (int k0 = 0; k0 < 512; k0 += 64) {
        const int gch = (cc ^ srw) * 8;
#pragma unroll
        for (int r = 0; r < 2; ++r) {
            int row = r * 32 + wid * 8 + srw;
            gload16(A + (size_t)(m0 + row) * 512 + k0 + gch,
                    lA + (r * 32 + wid * 8) * 64);
            gload16(B + (size_t)(n0 + row) * 512 + k0 + gch,
                    lB + (r * 32 + wid * 8) * 64);
        }
        __syncthreads();
        s16x8 af[2][2], bfr[2][2];
        const int sa = arow & 7;
#pragma unroll
        for (int f = 0; f < 2; ++f) {
            int ra = (wm * 32 + f * 16 + arow) * 64;
            int rb = (wn * 32 + f * 16 + arow) * 64;
#pragma unroll
            for (int ks = 0; ks < 2; ++ks) {
                int q = ks * 4 + khi;
                af[ks][f]  = *(const s16x8*)&lA[ra + ((q ^ sa) << 3)];
                bfr[ks][f] = *(const s16x8*)&lB[rb + ((q ^ sa) << 3)];
            }
        }
#pragma unroll
        for (int ks = 0; ks < 2; ++ks)
#pragma unroll
            for (int i = 0; i < 2; ++i)
#pragma unroll
                for (int jj = 0; jj < 2; ++jj)
                    acc[i][jj] = __builtin_amdgcn_mfma_f32_16x16x32_bf16(
                        af[ks][i], bfr[ks][jj], acc[i][jj], 0, 0, 0);
        __syncthreads();
    }

#pragma unroll
    for (int i = 0; i < 2; ++i) {
        int gr0 = m0 + wm * 32 + i * 16 + khi * 4;
#pragma unroll
        for (int jj = 0; jj < 2; ++jj) {
            int gc = n0 + wn * 32 + jj * 16 + arow;
            if (gc >= 85) continue;
            float bb = bias[gc];
#pragma unroll
            for (int r = 0; r < 4; ++r)
                D[(size_t)(gr0 + r) * 85 + gc] = acc[i][jj][r] + bb;
        }
    }
}

extern "C" void kernel_launch(void* const* d_in, const int* in_sizes, int n_in,
                              void* d_out, int out_size, void* d_ws, size_t ws_size,
                              hipStream_t stream) {
    const float* x          = (const float*)d_in[0];
    const int*   idx        = (const int*)d_in[1];
    const float* stem_w     = (const float*)d_in[2];
    const float* stem_b     = (const float*)d_in[3];
    const float* cls_conv_w = (const float*)d_in[4];
    const float* cls_conv_b = (const float*)d_in[5];
    const float* reg_conv_w = (const float*)d_in[6];
    const float* reg_conv_b = (const float*)d_in[7];
    const float* cls_pred_w = (const float*)d_in[8];
    const float* cls_pred_b = (const float*)d_in[9];
    const float* reg_pred_w = (const float*)d_in[10];
    const float* reg_pred_b = (const float*)d_in[11];
    const float* obj_pred_w = (const float*)d_in[12];
    const float* obj_pred_b = (const float*)d_in[13];
    float* out = (float*)d_out;
    char* ws = (char*)d_ws;

    u16*  stem   = (u16*)(ws);                    // 26,214,400 (NHWC bf16)
    u16*  feat   = (u16*)(ws + 26214400);         // 16,777,216
    u16*  Wc     = (u16*)(ws + 42991616);         // 2,359,296
    u16*  Wf     = (u16*)(ws + 45350912);         // 131,072
    u16*  Wsb    = (u16*)(ws + 45481984);         // 131,072
    int*  rowoff = (int*)(ws + 45613056);         // 589,824
    u16*  zpage  = (u16*)(ws + 46202880);         // 512 B
    float* bc    = (float*)(ws + 46203392);       // 2048
    float* bp    = (float*)(ws + 46205440);       // 512

    // K0: tiny Wsb cast (the only input gemm_stem's B-path needs)
    wsb_prep<<<64, 256, 0, stream>>>(stem_w, Wsb);
    // K1: stem GEMM + all independent prep, one concurrent launch
    stem_prep<<<2721, 256, 0, stream>>>(x, idx, Wsb, stem_b,
                                        cls_conv_w, cls_conv_b, reg_conv_w, reg_conv_b,
                                        cls_pred_w, cls_pred_b, reg_pred_w, reg_pred_b,
                                        obj_pred_w, obj_pred_b,
                                        stem, Wc, Wf, rowoff, bc, bp, zpage);
    // K3 fused gather+conv: feat = silu(gather(stem) @ Wc^T + bc)  [16384][512]
    gemm_conv<<<dim3(128, 8), 256, 0, stream>>>(stem, rowoff, zpage, Wc, bc, feat);
    // K4: out[n][p<85] = feat @ Wf^T + bp  (f32 store)
    gemm_pred<<<dim3(256, 2), 256, 0, stream>>>(feat, Wf, bp, out);
}

// Round 16
// 92.295 us; speedup vs baseline: 1.1382x; 1.1382x over previous
//
#include <hip/hip_runtime.h>

typedef unsigned short u16;
typedef __attribute__((ext_vector_type(4))) float f32x4;
typedef __attribute__((ext_vector_type(8))) short s16x8;

__device__ inline float bf2f(u16 u) {
    unsigned v = ((unsigned)u) << 16;
    return __builtin_bit_cast(float, v);
}
__device__ inline u16 f2bf(float f) {
    unsigned u = __builtin_bit_cast(unsigned, f);
    unsigned r = (u + 0x7FFFu + ((u >> 16) & 1u)) >> 16;
    return (u16)r;
}

typedef const __attribute__((address_space(1))) void* gptr_t;
typedef __attribute__((address_space(3))) void* lptr_t;
__device__ inline void gload16(const u16* gp, u16* lp) {
    __builtin_amdgcn_global_load_lds((gptr_t)gp, (lptr_t)lp, 16, 0, 0);
}

// ---------------- fused_pre (r10 verified): weight permutes + rowoff + biases ------------
__global__ __launch_bounds__(256) void fused_pre(
    const int* __restrict__ idx,
    const float* __restrict__ stem_w,
    const float* __restrict__ cls_conv_w, const float* __restrict__ cls_conv_b,
    const float* __restrict__ reg_conv_w, const float* __restrict__ reg_conv_b,
    const float* __restrict__ cls_pred_w, const float* __restrict__ cls_pred_b,
    const float* __restrict__ reg_pred_w, const float* __restrict__ reg_pred_b,
    const float* __restrict__ obj_pred_w, const float* __restrict__ obj_pred_b,
    u16* __restrict__ Wsb, u16* __restrict__ Wc,
    u16* __restrict__ Wf, int* __restrict__ rowoff,
    float* __restrict__ bc, float* __restrict__ bp, u16* __restrict__ zpage) {
    const int blk = blockIdx.x;
    const int t = threadIdx.x;

    if (blk < 512) {                       // ---- Wc permute ----
        int o = blk;
        const float* src = (o < 256) ? (cls_conv_w + (size_t)o * 2304)
                                     : (reg_conv_w + (size_t)(o - 256) * 2304);
        u16* dst = Wc + (size_t)o * 2304;
#pragma unroll
        for (int it = 0; it < 9; ++it) {
            int kk = it * 256 + t;
            int j = kk >> 8, c = kk & 255;
            dst[kk] = f2bf(src[c * 9 + j]);
        }
    } else if (blk < 1088) {               // ---- rowoff ----
        int i = (blk - 512) * 256 + t;
        int n = i / 9, j = i % 9;
        int b = idx[n * 3 + 0], y = idx[n * 3 + 1], xx0 = idx[n * 3 + 2];
        int yy = y + j / 3 - 1;
        int xx = xx0 + j % 3 - 1;
        rowoff[i] = ((unsigned)yy < 80u && (unsigned)xx < 80u)
                        ? (b * 6400 + yy * 80 + xx) * 256 : -1;
    } else if (blk < 1152) {               // ---- Wsb ----
        int base = (blk - 1088) * 1024;
#pragma unroll
        for (int it = 0; it < 4; ++it) {
            int i = base + it * 256 + t;
            Wsb[i] = f2bf(stem_w[i]);
        }
    } else if (blk < 1184) {               // ---- Wf ----
        int base = (blk - 1152) * 2048;
#pragma unroll
        for (int it = 0; it < 8; ++it) {
            int i = base + it * 256 + t;
            int o = i >> 9, k = i & 511;
            float v = 0.f;
            if (o < 4)       { if (k >= 256) v = reg_pred_w[o * 256 + (k - 256)]; }
            else if (o == 4) { if (k >= 256) v = obj_pred_w[k - 256]; }
            else if (o < 85) { if (k < 256)  v = cls_pred_w[(o - 5) * 256 + k]; }
            Wf[i] = f2bf(v);
        }
    } else {                               // ---- biases + zero page ----
        for (int i = t; i < 512; i += 256)
            bc[i] = (i < 256) ? cls_conv_b[i] : reg_conv_b[i - 256];
        if (t < 128) {
            float v = 0.f;
            if (t < 4) v = reg_pred_b[t];
            else if (t == 4) v = obj_pred_b[0];
            else if (t < 85) v = cls_pred_b[t - 5];
            bp[t] = v;
        }
        zpage[t] = 0;
    }
}

// ---------------- gemm_stem (r10 verified): stem = silu(x^T @ Wsb^T + b) -----------------
__global__ __launch_bounds__(256, 4) void gemm_stem(
    const float* __restrict__ x, const u16* __restrict__ Wsb,
    const float* __restrict__ bias, u16* __restrict__ stem) {
    __shared__ __align__(16) u16 lA[128 * 72];
    __shared__ __align__(16) u16 lB[64 * 64];
    const int tid = threadIdx.x;
    const int lane = tid & 63;
    const int wid = tid >> 6;
    const int wm = wid >> 1, wn = wid & 1;
    const int bx = blockIdx.x;             // 0..399 ; 50 blocks per image
    const int b   = bx / 50;
    const int hwb = (bx % 50) * 128;
    const int n0 = blockIdx.y * 64;

    const int srw = lane >> 3;
    const int cc  = lane & 7;
    const int gch = (cc ^ srw) * 8;
    const int arow = lane & 15;
    const int khi  = lane >> 4;
    const int sa   = arow & 7;

    const float* xb = x + (size_t)b * 256 * 6400 + hwb;
    const u16* Bp = Wsb + (size_t)(n0 + wid * 8 + srw) * 256 + gch;

    f32x4 acc[4][2] = {};

    for (int k0 = 0; k0 < 256; k0 += 64) {
#pragma unroll
        for (int r = 0; r < 2; ++r)
            gload16(Bp + (size_t)(r * 32) * 256 + k0,
                    lB + (r * 32 + wid * 8) * 64);
#pragma unroll
        for (int u = 0; u < 4; ++u) {
            const int hw  = (u & 1) * 64 + lane;
            const int oct = (u >> 1) * 4 + wid;
            union { u16 s[8]; s16x8 v; } pk;
#pragma unroll
            for (int jj = 0; jj < 8; ++jj)
                pk.s[jj] = f2bf(xb[(size_t)(k0 + oct * 8 + jj) * 6400 + hw]);
            *(s16x8*)&lA[hw * 72 + oct * 8] = pk.v;
        }
        __syncthreads();
        s16x8 af[2][4], bfr[2][2];
#pragma unroll
        for (int f = 0; f < 4; ++f) {
            int ra = (wm * 64 + f * 16 + arow) * 72;
#pragma unroll
            for (int ks = 0; ks < 2; ++ks)
                af[ks][f] = *(const s16x8*)&lA[ra + (ks * 4 + khi) * 8];
        }
#pragma unroll
        for (int jj = 0; jj < 2; ++jj) {
            int rb2 = (wn * 32 + jj * 16 + arow) * 64;
#pragma unroll
            for (int ks = 0; ks < 2; ++ks) {
                int q = ks * 4 + khi;
                bfr[ks][jj] = *(const s16x8*)&lB[rb2 + ((q ^ sa) << 3)];
            }
        }
#pragma unroll
        for (int ks = 0; ks < 2; ++ks)
#pragma unroll
            for (int i = 0; i < 4; ++i)
#pragma unroll
                for (int jj = 0; jj < 2; ++jj)
                    acc[i][jj] = __builtin_amdgcn_mfma_f32_16x16x32_bf16(
                        af[ks][i], bfr[ks][jj], acc[i][jj], 0, 0, 0);
        __syncthreads();
    }

#pragma unroll
    for (int i = 0; i < 4; ++i) {
        int lr0 = wm * 64 + i * 16 + khi * 4;
#pragma unroll
        for (int jj = 0; jj < 2; ++jj) {
            int gc = n0 + wn * 32 + jj * 16 + arow;
            float bb = bias[gc];
#pragma unroll
            for (int r = 0; r < 4; ++r) {
                float v = acc[i][jj][r] + bb;
                v = v / (1.0f + __expf(-v));
                stem[(size_t)(b * 6400 + hwb + lr0 + r) * 256 + gc] = f2bf(v);
            }
        }
    }
}

// ---------------- K3 fused (r9/r10 verified): 2-phase, hoisted rowoff, grid (128,8) -----
// Linearized id = by*128+bx -> XCD = bx%8: all 8 n-panels of an m-block colocate
// on one XCD, so the gathered A-rows are fetched once and reused 8x (r13 lesson).
__global__ __launch_bounds__(256, 4) void gemm_conv(
    const u16* __restrict__ stem, const int* __restrict__ rowoff,
    const u16* __restrict__ zpage, const u16* __restrict__ B,
    const float* __restrict__ bias, u16* __restrict__ D) {
    __shared__ __align__(16) u16 lA[128 * 64];
    __shared__ __align__(16) u16 lB[64 * 64];
    const int tid = threadIdx.x;
    const int lane = tid & 63;
    const int wid = tid >> 6;
    const int wm = wid >> 1, wn = wid & 1;
    const int m0 = blockIdx.x * 128;
    const int n0 = blockIdx.y * 64;

    const int srw = lane >> 3;
    const int cc  = lane & 7;
    const int gch = (cc ^ srw) * 8;
    const int arow = lane & 15;
    const int khi  = lane >> 4;
    const int sa   = arow & 7;

    int ro[4][9];
#pragma unroll
    for (int r = 0; r < 4; ++r) {
        const int rb = (m0 + r * 32 + wid * 8 + srw) * 9;
#pragma unroll
        for (int j = 0; j < 9; ++j) ro[r][j] = rowoff[rb + j];
    }
    const u16* Bp = B + (size_t)(n0 + wid * 8 + srw) * 2304 + gch;

    f32x4 acc[4][2] = {};

#pragma unroll
    for (int j = 0; j < 9; ++j) {
#pragma unroll
        for (int q4 = 0; q4 < 4; ++q4) {
            const int c0 = q4 << 6;
            const int k0 = j * 256 + c0;
#pragma unroll
            for (int r = 0; r < 2; ++r)
                gload16(Bp + (size_t)(r * 32) * 2304 + k0,
                        lB + (r * 32 + wid * 8) * 64);
#pragma unroll
            for (int r = 0; r < 4; ++r) {
                int roff = ro[r][j];
                const u16* srcA = (roff < 0) ? (zpage + gch)
                                             : (stem + roff + c0 + gch);
                gload16(srcA, lA + (r * 32 + wid * 8) * 64);
            }
            __syncthreads();
            s16x8 af[2][4], bfr[2][2];
#pragma unroll
            for (int f = 0; f < 4; ++f) {
                int ra = (wm * 64 + f * 16 + arow) * 64;
#pragma unroll
                for (int ks = 0; ks < 2; ++ks) {
                    int q = ks * 4 + khi;
                    af[ks][f] = *(const s16x8*)&lA[ra + ((q ^ sa) << 3)];
                }
            }
#pragma unroll
            for (int jj = 0; jj < 2; ++jj) {
                int rb2 = (wn * 32 + jj * 16 + arow) * 64;
#pragma unroll
                for (int ks = 0; ks < 2; ++ks) {
                    int q = ks * 4 + khi;
                    bfr[ks][jj] = *(const s16x8*)&lB[rb2 + ((q ^ sa) << 3)];
                }
            }
#pragma unroll
            for (int ks = 0; ks < 2; ++ks)
#pragma unroll
                for (int i = 0; i < 4; ++i)
#pragma unroll
                    for (int jj = 0; jj < 2; ++jj)
                        acc[i][jj] = __builtin_amdgcn_mfma_f32_16x16x32_bf16(
                            af[ks][i], bfr[ks][jj], acc[i][jj], 0, 0, 0);
            __syncthreads();
        }
    }

#pragma unroll
    for (int i = 0; i < 4; ++i) {
        int gr0 = m0 + wm * 64 + i * 16 + khi * 4;
#pragma unroll
        for (int jj = 0; jj < 2; ++jj) {
            int gc = n0 + wn * 32 + jj * 16 + arow;
            float bb = bias[gc];
#pragma unroll
            for (int r = 0; r < 4; ++r) {
                float v = acc[i][jj][r] + bb;
                v = v / (1.0f + __expf(-v));
                D[(size_t)(gr0 + r) * 512 + gc] = f2bf(v);
            }
        }
    }
}

// ---------------- K4 (r10 verified): out[m, p<85] = feat[m,:] @ Wf^T + bp ----------------
__global__ __launch_bounds__(256, 4) void gemm_pred(
    const u16* __restrict__ A, const u16* __restrict__ B,
    const float* __restrict__ bias, float* __restrict__ D) {
    __shared__ __align__(16) u16 lA[64 * 64];
    __shared__ __align__(16) u16 lB[64 * 64];
    const int tid = threadIdx.x;
    const int lane = tid & 63;
    const int wid = tid >> 6;
    const int wm = wid >> 1, wn = wid & 1;
    const int m0 = blockIdx.x * 64;
    const int n0 = blockIdx.y * 64;

    const int srw = lane >> 3;
    const int cc  = lane & 7;
    const int arow = lane & 15;
    const int khi  = lane >> 4;

    f32x4 acc[2][2] = {};

    for (int k0 = 0; k0 < 512; k0 += 64) {
        const int gch = (cc ^ srw) * 8;
#pragma unroll
        for (int r = 0; r < 2; ++r) {
            int row = r * 32 + wid * 8 + srw;
            gload16(A + (size_t)(m0 + row) * 512 + k0 + gch,
                    lA + (r * 32 + wid * 8) * 64);
            gload16(B + (size_t)(n0 + row) * 512 + k0 + gch,
                    lB + (r * 32 + wid * 8) * 64);
        }
        __syncthreads();
        s16x8 af[2][2], bfr[2][2];
        const int sa = arow & 7;
#pragma unroll
        for (int f = 0; f < 2; ++f) {
            int ra = (wm * 32 + f * 16 + arow) * 64;
            int rb = (wn * 32 + f * 16 + arow) * 64;
#pragma unroll
            for (int ks = 0; ks < 2; ++ks) {
                int q = ks * 4 + khi;
                af[ks][f]  = *(const s16x8*)&lA[ra + ((q ^ sa) << 3)];
                bfr[ks][f] = *(const s16x8*)&lB[rb + ((q ^ sa) << 3)];
            }
        }
#pragma unroll
        for (int ks = 0; ks < 2; ++ks)
#pragma unroll
            for (int i = 0; i < 2; ++i)
#pragma unroll
                for (int jj = 0; jj < 2; ++jj)
                    acc[i][jj] = __builtin_amdgcn_mfma_f32_16x16x32_bf16(
                        af[ks][i], bfr[ks][jj], acc[i][jj], 0, 0, 0);
        __syncthreads();
    }

#pragma unroll
    for (int i = 0; i < 2; ++i) {
        int gr0 = m0 + wm * 32 + i * 16 + khi * 4;
#pragma unroll
        for (int jj = 0; jj < 2; ++jj) {
            int gc = n0 + wn * 32 + jj * 16 + arow;
            if (gc >= 85) continue;
            float bb = bias[gc];
#pragma unroll
            for (int r = 0; r < 4; ++r)
                D[(size_t)(gr0 + r) * 85 + gc] = acc[i][jj][r] + bb;
        }
    }
}

extern "C" void kernel_launch(void* const* d_in, const int* in_sizes, int n_in,
                              void* d_out, int out_size, void* d_ws, size_t ws_size,
                              hipStream_t stream) {
    const float* x          = (const float*)d_in[0];
    const int*   idx        = (const int*)d_in[1];
    const float* stem_w     = (const float*)d_in[2];
    const float* stem_b     = (const float*)d_in[3];
    const float* cls_conv_w = (const float*)d_in[4];
    const float* cls_conv_b = (const float*)d_in[5];
    const float* reg_conv_w = (const float*)d_in[6];
    const float* reg_conv_b = (const float*)d_in[7];
    const float* cls_pred_w = (const float*)d_in[8];
    const float* cls_pred_b = (const float*)d_in[9];
    const float* reg_pred_w = (const float*)d_in[10];
    const float* reg_pred_b = (const float*)d_in[11];
    const float* obj_pred_w = (const float*)d_in[12];
    const float* obj_pred_b = (const float*)d_in[13];
    float* out = (float*)d_out;
    char* ws = (char*)d_ws;

    u16*  stem   = (u16*)(ws);                    // 26,214,400 (NHWC bf16)
    u16*  feat   = (u16*)(ws + 26214400);         // 16,777,216
    u16*  Wc     = (u16*)(ws + 42991616);         // 2,359,296
    u16*  Wf     = (u16*)(ws + 45350912);         // 131,072
    u16*  Wsb    = (u16*)(ws + 45481984);         // 131,072
    int*  rowoff = (int*)(ws + 45613056);         // 589,824
    u16*  zpage  = (u16*)(ws + 46202880);         // 512 B
    float* bc    = (float*)(ws + 46203392);       // 2048
    float* bp    = (float*)(ws + 46205440);       // 512

    fused_pre<<<1185, 256, 0, stream>>>(idx, stem_w,
                                        cls_conv_w, cls_conv_b, reg_conv_w, reg_conv_b,
                                        cls_pred_w, cls_pred_b, reg_pred_w, reg_pred_b,
                                        obj_pred_w, obj_pred_b,
                                        Wsb, Wc, Wf, rowoff, bc, bp, zpage);
    // K1: stem = silu(x^T @ stem_w^T + b) -> NHWC bf16 [51200][256], transpose fused
    gemm_stem<<<dim3(400, 4), 256, 0, stream>>>(x, Wsb, stem_b, stem);
    // K3 fused gather+conv: feat = silu(gather(stem) @ Wc^T + bc)  [16384][512]
    gemm_conv<<<dim3(128, 8), 256, 0, stream>>>(stem, rowoff, zpage, Wc, bc, feat);
    // K4: out[n][p<85] = feat @ Wf^T + bp  (f32 store)
    gemm_pred<<<dim3(256, 2), 256, 0, stream>>>(feat, Wf, bp, out);
}